// Round 4
// baseline (284.899 us; speedup 1.0000x reference)
//
#include <hip/hip_runtime.h>
#include <hip/hip_bf16.h>

#define N_HALF 4096
#define M_TOT  8192
#define D      256
#define TJ     64          // j-rows staged in LDS per jt
#define JCHUNK 256         // j-cols per block
#define ZJ_STRIDE 264      // 256 + 8 bf16 pad (row = 528 B, 16B-aligned)
#define C_LOG2E_2 2.88539008177793f   // 2*log2(e)

typedef __attribute__((ext_vector_type(8))) short bf16x8;
typedef __attribute__((ext_vector_type(4))) float f32x4;

__device__ __forceinline__ float wave_reduce_sum(float v) {
    v += __shfl_xor(v, 1);
    v += __shfl_xor(v, 2);
    v += __shfl_xor(v, 4);
    v += __shfl_xor(v, 8);
    v += __shfl_xor(v, 16);
    v += __shfl_xor(v, 32);
    return v;
}

// One wave per pair r: normalize reps row r (=zjs[r]) and r+N (=zis[r]),
// fp32 positive-pair dot, zero rowsum. No barriers, float4 loads.
__global__ __launch_bounds__(256)
void k_prep(const float* __restrict__ zis, const float* __restrict__ zjs,
            __hip_bfloat16* __restrict__ zn, float* __restrict__ rowsum,
            float* __restrict__ pos_part) {
    int tid  = threadIdx.x;
    int r    = blockIdx.x * 4 + (tid >> 6);   // 0..4095
    int lane = tid & 63;
    const float4 zi4 = *reinterpret_cast<const float4*>(zis + (size_t)r * D + lane * 4);
    const float4 zj4 = *reinterpret_cast<const float4*>(zjs + (size_t)r * D + lane * 4);
    float ssi = zi4.x * zi4.x + zi4.y * zi4.y + zi4.z * zi4.z + zi4.w * zi4.w;
    float ssj = zj4.x * zj4.x + zj4.y * zj4.y + zj4.z * zj4.z + zj4.w * zj4.w;
    float dd  = zi4.x * zj4.x + zi4.y * zj4.y + zi4.z * zj4.z + zi4.w * zj4.w;
    ssi = wave_reduce_sum(ssi);
    ssj = wave_reduce_sum(ssj);
    dd  = wave_reduce_sum(dd);
    float ni = fmaxf(sqrtf(ssi), 1e-8f);
    float nj = fmaxf(sqrtf(ssj), 1e-8f);
    float rin = 1.0f / ni, rjn = 1.0f / nj;
    ushort4 oj, oi;
    oj.x = __bfloat16_as_ushort(__float2bfloat16(zj4.x * rjn));
    oj.y = __bfloat16_as_ushort(__float2bfloat16(zj4.y * rjn));
    oj.z = __bfloat16_as_ushort(__float2bfloat16(zj4.z * rjn));
    oj.w = __bfloat16_as_ushort(__float2bfloat16(zj4.w * rjn));
    oi.x = __bfloat16_as_ushort(__float2bfloat16(zi4.x * rin));
    oi.y = __bfloat16_as_ushort(__float2bfloat16(zi4.y * rin));
    oi.z = __bfloat16_as_ushort(__float2bfloat16(zi4.z * rin));
    oi.w = __bfloat16_as_ushort(__float2bfloat16(zi4.w * rin));
    ushort* znu = reinterpret_cast<ushort*>(zn);
    *reinterpret_cast<ushort4*>(znu + (size_t)r * D + lane * 4)            = oj;
    *reinterpret_cast<ushort4*>(znu + (size_t)(r + N_HALF) * D + lane * 4) = oi;
    if (lane == 0) {
        // sum over all 2N rows of pos_i = sim/T; each unordered pair twice -> *4
        pos_part[r] = dd * rin * rjn * 4.0f;
    }
    if (tid < 8) rowsum[blockIdx.x * 8 + tid] = 0.0f;
}

// Fused sim + exp + row-sum, register-blocked A.
// Block: 256 thr = 4 waves; block tile = 256 i-rows x 256 j-cols.
// Wave w owns i-rows [blk*256 + w*64, +64) as 4 MFMA i-tiles whose A fragments
// (full K=256) live in 128 VGPRs -> each LDS B-frag read feeds 4 MFMAs.
// rowsum[i] += sum_j exp(sim_ij*2 - 2)   (diag included; subtract 1 in k_final)
__global__ __launch_bounds__(256, 4)
void k_main(const __hip_bfloat16* __restrict__ znh, float* __restrict__ rowsum) {
    __shared__ __align__(16) ushort zj[TJ * ZJ_STRIDE];   // 33792 B
    const ushort* zn = reinterpret_cast<const ushort*>(znh);
    int tid  = threadIdx.x;
    int wave = tid >> 6;
    int lane = tid & 63;
    int q    = lane >> 4;   // quad
    int li   = lane & 15;
    int i_base = blockIdx.x * 256 + wave * 64;
    int j0     = blockIdx.y * JCHUNK;

    // A fragment (16x16x32 bf16): A[m][k], m = lane&15, k = quad*8 + j
    bf16x8 afrag[4][8];
#pragma unroll
    for (int it = 0; it < 4; ++it) {
        const ushort* ap = zn + (((size_t)(i_base + it * 16 + li)) << 8) + q * 8;
#pragma unroll
        for (int kt = 0; kt < 8; ++kt)
            afrag[it][kt] = *reinterpret_cast<const bf16x8*>(ap + kt * 32);
    }

    float part[4][4];   // [i_tile][reg-row]
#pragma unroll
    for (int it = 0; it < 4; ++it)
#pragma unroll
        for (int r = 0; r < 4; ++r) part[it][r] = 0.0f;

    for (int jt = 0; jt < JCHUNK / TJ; ++jt) {
        __syncthreads();   // previous iteration's reads done before overwrite
        {
            int base = j0 + jt * TJ;
#pragma unroll
            for (int s = 0; s < 8; ++s) {
                int e  = (s * 256 + tid) * 8;
                int rr = e >> 8;
                int cc = e & 255;
                *reinterpret_cast<uint4*>(&zj[rr * ZJ_STRIDE + cc]) =
                    *reinterpret_cast<const uint4*>(zn + (((size_t)(base + rr)) << 8) + cc);
            }
        }
        __syncthreads();

#pragma unroll
        for (int jtile = 0; jtile < 4; ++jtile) {
            f32x4 acc[4] = {{0,0,0,0},{0,0,0,0},{0,0,0,0},{0,0,0,0}};
#pragma unroll
            for (int kt = 0; kt < 8; ++kt) {
                // B frag: B[k][n], n = li -> zj row (jtile*16 + li), k = kt*32 + q*8
                bf16x8 b = *reinterpret_cast<const bf16x8*>(
                    &zj[(jtile * 16 + li) * ZJ_STRIDE + kt * 32 + q * 8]);
#pragma unroll
                for (int it = 0; it < 4; ++it)
                    acc[it] = __builtin_amdgcn_mfma_f32_16x16x32_bf16(
                        afrag[it][kt], b, acc[it], 0, 0, 0);
            }
            // C/D layout (m89-verified): col = lane&15, row = quad*4 + reg
            // exp(2s-2) = exp2(C_LOG2E_2*s - C_LOG2E_2): one v_fma + one v_exp
#pragma unroll
            for (int it = 0; it < 4; ++it)
#pragma unroll
                for (int r = 0; r < 4; ++r)
                    part[it][r] += exp2f(__builtin_fmaf(acc[it][r], C_LOG2E_2, -C_LOG2E_2));
        }
    }

    // Reduce across the 16 lanes holding different j-cols of the same rows.
#pragma unroll
    for (int it = 0; it < 4; ++it)
#pragma unroll
        for (int r = 0; r < 4; ++r) {
            float v = part[it][r];
            v += __shfl_xor(v, 1);
            v += __shfl_xor(v, 2);
            v += __shfl_xor(v, 4);
            v += __shfl_xor(v, 8);
            if (li == 0) atomicAdd(&rowsum[i_base + it * 16 + q * 4 + r], v);
        }
}

// lse_i = 2 + log(rowsum_i - 1); loss = (sum lse - sum pos)/M
__global__ __launch_bounds__(1024)
void k_final(const float* __restrict__ rowsum, const float* __restrict__ pos_part,
             float* __restrict__ out) {
    int t = threadIdx.x;
    float acc = 0.0f;
    for (int i = t; i < M_TOT; i += 1024)
        acc += 2.0f + __logf(rowsum[i] - 1.0f);
    float pacc = 0.0f;
    for (int i = t; i < N_HALF; i += 1024)
        pacc += pos_part[i];
    acc  = wave_reduce_sum(acc);
    pacc = wave_reduce_sum(pacc);
    __shared__ float wsum[16], psum[16];
    if ((t & 63) == 0) { wsum[t >> 6] = acc; psum[t >> 6] = pacc; }
    __syncthreads();
    if (t == 0) {
        float tot = 0.0f, pt = 0.0f;
#pragma unroll
        for (int w = 0; w < 16; ++w) { tot += wsum[w]; pt += psum[w]; }
        out[0] = (tot - pt) / (float)M_TOT;
    }
}

extern "C" void kernel_launch(void* const* d_in, const int* in_sizes, int n_in,
                              void* d_out, int out_size, void* d_ws, size_t ws_size,
                              hipStream_t stream) {
    const float* zis = (const float*)d_in[0];
    const float* zjs = (const float*)d_in[1];
    char* ws = (char*)d_ws;
    __hip_bfloat16* zn = (__hip_bfloat16*)ws;                         // 4 MB
    float* rowsum   = (float*)(ws + (size_t)M_TOT * D * 2);           // 32 KB
    float* pos_part = rowsum + M_TOT;                                 // 16 KB
    float* out = (float*)d_out;

    k_prep<<<N_HALF / 4, 256, 0, stream>>>(zis, zjs, zn, rowsum, pos_part);
    dim3 grid(M_TOT / 256, M_TOT / JCHUNK);
    k_main<<<grid, 256, 0, stream>>>(zn, rowsum);
    k_final<<<1, 1024, 0, stream>>>(rowsum, pos_part, out);
}

// Round 5
// 187.928 us; speedup vs baseline: 1.5160x; 1.5160x over previous
//
#include <hip/hip_runtime.h>
#include <hip/hip_bf16.h>

#define N_HALF 4096
#define M_TOT  8192
#define D      256
#define TJ     64          // j-rows staged in LDS per jt
#define JCHUNK 256         // j-cols per block
#define NBLOCKS ((M_TOT / 256) * (M_TOT / JCHUNK))   // 1024
#define ZJ_STRIDE 264      // 256 + 8 bf16 pad (row = 528 B, 16B-aligned)
#define C_LOG2E_2 2.88539008177793f   // 2*log2(e)

typedef __attribute__((ext_vector_type(8))) short bf16x8;
typedef __attribute__((ext_vector_type(4))) float f32x4;

__device__ __forceinline__ float wave_reduce_sum(float v) {
    v += __shfl_xor(v, 1);
    v += __shfl_xor(v, 2);
    v += __shfl_xor(v, 4);
    v += __shfl_xor(v, 8);
    v += __shfl_xor(v, 16);
    v += __shfl_xor(v, 32);
    return v;
}

// One wave per pair r: normalize reps row r (=zjs[r]) and r+N (=zis[r]),
// fp32 positive-pair dot, zero rowsum + done counter. No barriers, float4 loads.
__global__ __launch_bounds__(256)
void k_prep(const float* __restrict__ zis, const float* __restrict__ zjs,
            __hip_bfloat16* __restrict__ zn, float* __restrict__ rowsum,
            float* __restrict__ pos_part, unsigned* __restrict__ done_ctr) {
    int tid  = threadIdx.x;
    int r    = blockIdx.x * 4 + (tid >> 6);   // 0..4095
    int lane = tid & 63;
    const float4 zi4 = *reinterpret_cast<const float4*>(zis + (size_t)r * D + lane * 4);
    const float4 zj4 = *reinterpret_cast<const float4*>(zjs + (size_t)r * D + lane * 4);
    float ssi = zi4.x * zi4.x + zi4.y * zi4.y + zi4.z * zi4.z + zi4.w * zi4.w;
    float ssj = zj4.x * zj4.x + zj4.y * zj4.y + zj4.z * zj4.z + zj4.w * zj4.w;
    float dd  = zi4.x * zj4.x + zi4.y * zj4.y + zi4.z * zj4.z + zi4.w * zj4.w;
    ssi = wave_reduce_sum(ssi);
    ssj = wave_reduce_sum(ssj);
    dd  = wave_reduce_sum(dd);
    float ni = fmaxf(sqrtf(ssi), 1e-8f);
    float nj = fmaxf(sqrtf(ssj), 1e-8f);
    float rin = 1.0f / ni, rjn = 1.0f / nj;
    ushort4 oj, oi;
    oj.x = __bfloat16_as_ushort(__float2bfloat16(zj4.x * rjn));
    oj.y = __bfloat16_as_ushort(__float2bfloat16(zj4.y * rjn));
    oj.z = __bfloat16_as_ushort(__float2bfloat16(zj4.z * rjn));
    oj.w = __bfloat16_as_ushort(__float2bfloat16(zj4.w * rjn));
    oi.x = __bfloat16_as_ushort(__float2bfloat16(zi4.x * rin));
    oi.y = __bfloat16_as_ushort(__float2bfloat16(zi4.y * rin));
    oi.z = __bfloat16_as_ushort(__float2bfloat16(zi4.z * rin));
    oi.w = __bfloat16_as_ushort(__float2bfloat16(zi4.w * rin));
    ushort* znu = reinterpret_cast<ushort*>(zn);
    *reinterpret_cast<ushort4*>(znu + (size_t)r * D + lane * 4)            = oj;
    *reinterpret_cast<ushort4*>(znu + (size_t)(r + N_HALF) * D + lane * 4) = oi;
    if (lane == 0) {
        // sum over all 2N rows of pos_i = sim/T; each unordered pair twice -> *4
        pos_part[r] = dd * rin * rjn * 4.0f;
    }
    if (tid < 8) rowsum[blockIdx.x * 8 + tid] = 0.0f;
    if (blockIdx.x == 0 && tid == 0) *done_ctr = 0u;
}

// Fused sim + exp + row-sum, register-blocked A; last block computes the loss.
// Block: 256 thr = 4 waves; block tile = 256 i-rows x 256 j-cols.
// Wave w owns i-rows [blk*256 + w*64, +64) as 4 MFMA i-tiles whose A fragments
// (full K=256) live in 128 VGPRs -> each LDS B-frag read feeds 4 MFMAs.
// NOTE: do NOT raise min-waves/EU here — __launch_bounds__(256,4) capped the
// unified regfile at 128/wave, spilled afrag to scratch (FETCH 612 MB, 4x slow).
__global__ __launch_bounds__(256, 2)
void k_main(const __hip_bfloat16* __restrict__ znh, float* __restrict__ rowsum,
            const float* __restrict__ pos_part, unsigned* __restrict__ done_ctr,
            float* __restrict__ out) {
    __shared__ __align__(16) ushort zj[TJ * ZJ_STRIDE];   // 33792 B
    const ushort* zn = reinterpret_cast<const ushort*>(znh);
    int tid  = threadIdx.x;
    int wave = tid >> 6;
    int lane = tid & 63;
    int q    = lane >> 4;   // quad
    int li   = lane & 15;
    int i_base = blockIdx.x * 256 + wave * 64;
    int j0     = blockIdx.y * JCHUNK;

    // A fragment (16x16x32 bf16): A[m][k], m = lane&15, k = quad*8 + j
    bf16x8 afrag[4][8];
#pragma unroll
    for (int it = 0; it < 4; ++it) {
        const ushort* ap = zn + (((size_t)(i_base + it * 16 + li)) << 8) + q * 8;
#pragma unroll
        for (int kt = 0; kt < 8; ++kt)
            afrag[it][kt] = *reinterpret_cast<const bf16x8*>(ap + kt * 32);
    }

    float part[4][4];   // [i_tile][reg-row]
#pragma unroll
    for (int it = 0; it < 4; ++it)
#pragma unroll
        for (int r = 0; r < 4; ++r) part[it][r] = 0.0f;

    for (int jt = 0; jt < JCHUNK / TJ; ++jt) {
        __syncthreads();   // previous iteration's reads done before overwrite
        {
            int base = j0 + jt * TJ;
#pragma unroll
            for (int s = 0; s < 8; ++s) {
                int e  = (s * 256 + tid) * 8;
                int rr = e >> 8;
                int cc = e & 255;
                *reinterpret_cast<uint4*>(&zj[rr * ZJ_STRIDE + cc]) =
                    *reinterpret_cast<const uint4*>(zn + (((size_t)(base + rr)) << 8) + cc);
            }
        }
        __syncthreads();

#pragma unroll
        for (int jtile = 0; jtile < 4; ++jtile) {
            f32x4 acc[4] = {{0,0,0,0},{0,0,0,0},{0,0,0,0},{0,0,0,0}};
#pragma unroll
            for (int kt = 0; kt < 8; ++kt) {
                // B frag: B[k][n], n = li -> zj row (jtile*16 + li), k = kt*32 + q*8
                bf16x8 b = *reinterpret_cast<const bf16x8*>(
                    &zj[(jtile * 16 + li) * ZJ_STRIDE + kt * 32 + q * 8]);
#pragma unroll
                for (int it = 0; it < 4; ++it)
                    acc[it] = __builtin_amdgcn_mfma_f32_16x16x32_bf16(
                        afrag[it][kt], b, acc[it], 0, 0, 0);
            }
            // C/D layout (m89-verified): col = lane&15, row = quad*4 + reg
            // exp(2s-2) = exp2(2log2e*s - 2log2e): one v_fma + one v_exp
#pragma unroll
            for (int it = 0; it < 4; ++it)
#pragma unroll
                for (int r = 0; r < 4; ++r)
                    part[it][r] += exp2f(__builtin_fmaf(acc[it][r], C_LOG2E_2, -C_LOG2E_2));
        }
    }

    // Reduce across the 16 lanes holding different j-cols of the same rows.
#pragma unroll
    for (int it = 0; it < 4; ++it)
#pragma unroll
        for (int r = 0; r < 4; ++r) {
            float v = part[it][r];
            v += __shfl_xor(v, 1);
            v += __shfl_xor(v, 2);
            v += __shfl_xor(v, 4);
            v += __shfl_xor(v, 8);
            if (li == 0) atomicAdd(&rowsum[i_base + it * 16 + q * 4 + r], v);
        }

    // Last-block-done: final reduction fused in (saves a ~20us launch gap).
    __threadfence();
    __shared__ unsigned lastv;
    if (tid == 0) lastv = atomicAdd(done_ctr, 1u);
    __syncthreads();
    if (lastv == NBLOCKS - 1) {
        // Read rowsum through the same device-coherence point the writers used.
        float acc = 0.0f;
        for (int i = tid; i < M_TOT; i += 256) {
            float v = atomicAdd(&rowsum[i], 0.0f);   // atomic load
            acc += 2.0f + __logf(v - 1.0f);          // lse_i (diag's exp(0)=1 removed)
        }
        float pacc = 0.0f;
        for (int i = tid; i < N_HALF; i += 256)
            pacc += pos_part[i];
        acc  = wave_reduce_sum(acc);
        pacc = wave_reduce_sum(pacc);
        __shared__ float wsum[4], psum[4];
        if ((tid & 63) == 0) { wsum[tid >> 6] = acc; psum[tid >> 6] = pacc; }
        __syncthreads();
        if (tid == 0) {
            float tot = wsum[0] + wsum[1] + wsum[2] + wsum[3];
            float pt  = psum[0] + psum[1] + psum[2] + psum[3];
            out[0] = (tot - pt) / (float)M_TOT;
        }
    }
}

extern "C" void kernel_launch(void* const* d_in, const int* in_sizes, int n_in,
                              void* d_out, int out_size, void* d_ws, size_t ws_size,
                              hipStream_t stream) {
    const float* zis = (const float*)d_in[0];
    const float* zjs = (const float*)d_in[1];
    char* ws = (char*)d_ws;
    __hip_bfloat16* zn = (__hip_bfloat16*)ws;                         // 4 MB
    float* rowsum   = (float*)(ws + (size_t)M_TOT * D * 2);           // 32 KB
    float* pos_part = rowsum + M_TOT;                                 // 16 KB
    unsigned* done_ctr = (unsigned*)(pos_part + N_HALF);              // 4 B
    float* out = (float*)d_out;

    k_prep<<<N_HALF / 4, 256, 0, stream>>>(zis, zjs, zn, rowsum, pos_part, done_ctr);
    dim3 grid(M_TOT / 256, M_TOT / JCHUNK);
    k_main<<<grid, 256, 0, stream>>>(zn, rowsum, pos_part, done_ctr, (float*)d_out);
}

// Round 6
// 175.580 us; speedup vs baseline: 1.6226x; 1.0703x over previous
//
#include <hip/hip_runtime.h>
#include <hip/hip_bf16.h>

#define N_HALF 4096
#define M_TOT  8192
#define D      256
#define TJ     64          // j-rows staged in LDS per jt
#define JCHUNK 512         // j-cols per block (8 jt iterations - keeps loop un-unrolled)
#define NJT    (JCHUNK / TJ)
#define NBLOCKS ((M_TOT / 256) * (M_TOT / JCHUNK))   // 32*16 = 512
#define ZJ_STRIDE 264      // 256 + 8 bf16 pad (row = 528 B, 16B-aligned)
#define C_LOG2E_2 2.88539008177793f   // 2*log2(e)

typedef __attribute__((ext_vector_type(8))) short bf16x8;
typedef __attribute__((ext_vector_type(4))) float f32x4;

__device__ __forceinline__ float wave_reduce_sum(float v) {
    v += __shfl_xor(v, 1);
    v += __shfl_xor(v, 2);
    v += __shfl_xor(v, 4);
    v += __shfl_xor(v, 8);
    v += __shfl_xor(v, 16);
    v += __shfl_xor(v, 32);
    return v;
}

// One wave per pair r: normalize reps row r (=zjs[r]) and r+N (=zis[r]),
// fp32 positive-pair dot, zero rowsum + done counter. No barriers, float4 loads.
__global__ __launch_bounds__(256)
void k_prep(const float* __restrict__ zis, const float* __restrict__ zjs,
            __hip_bfloat16* __restrict__ zn, float* __restrict__ rowsum,
            float* __restrict__ pos_part, unsigned* __restrict__ done_ctr) {
    int tid  = threadIdx.x;
    int r    = blockIdx.x * 4 + (tid >> 6);   // 0..4095
    int lane = tid & 63;
    const float4 zi4 = *reinterpret_cast<const float4*>(zis + (size_t)r * D + lane * 4);
    const float4 zj4 = *reinterpret_cast<const float4*>(zjs + (size_t)r * D + lane * 4);
    float ssi = zi4.x * zi4.x + zi4.y * zi4.y + zi4.z * zi4.z + zi4.w * zi4.w;
    float ssj = zj4.x * zj4.x + zj4.y * zj4.y + zj4.z * zj4.z + zj4.w * zj4.w;
    float dd  = zi4.x * zj4.x + zi4.y * zj4.y + zi4.z * zj4.z + zi4.w * zj4.w;
    ssi = wave_reduce_sum(ssi);
    ssj = wave_reduce_sum(ssj);
    dd  = wave_reduce_sum(dd);
    float ni = fmaxf(sqrtf(ssi), 1e-8f);
    float nj = fmaxf(sqrtf(ssj), 1e-8f);
    float rin = 1.0f / ni, rjn = 1.0f / nj;
    ushort4 oj, oi;
    oj.x = __bfloat16_as_ushort(__float2bfloat16(zj4.x * rjn));
    oj.y = __bfloat16_as_ushort(__float2bfloat16(zj4.y * rjn));
    oj.z = __bfloat16_as_ushort(__float2bfloat16(zj4.z * rjn));
    oj.w = __bfloat16_as_ushort(__float2bfloat16(zj4.w * rjn));
    oi.x = __bfloat16_as_ushort(__float2bfloat16(zi4.x * rin));
    oi.y = __bfloat16_as_ushort(__float2bfloat16(zi4.y * rin));
    oi.z = __bfloat16_as_ushort(__float2bfloat16(zi4.z * rin));
    oi.w = __bfloat16_as_ushort(__float2bfloat16(zi4.w * rin));
    ushort* znu = reinterpret_cast<ushort*>(zn);
    *reinterpret_cast<ushort4*>(znu + (size_t)r * D + lane * 4)            = oj;
    *reinterpret_cast<ushort4*>(znu + (size_t)(r + N_HALF) * D + lane * 4) = oi;
    if (lane == 0) {
        // sum over all 2N rows of pos_i = sim/T; each unordered pair twice -> *4
        pos_part[r] = dd * rin * rjn * 4.0f;
    }
    if (tid < 8) rowsum[blockIdx.x * 8 + tid] = 0.0f;
    if (blockIdx.x == 0 && tid == 0) *done_ctr = 0u;
}

// Fused sim + exp + row-sum; last block computes the loss.
// Block: 256 thr = 4 waves; block tile = 256 i-rows x 512 j-cols.
// Wave w holds i-rows [blk*256 + w*64, +64) as 4 MFMA i-tiles, A frags (full
// K=256) resident in 128 VGPRs. B tiles are software-pipelined: next tile is
// prefetched into 8xuint4 registers while the current tile computes.
// NOTE: jt loop MUST stay un-unrolled (#pragma unroll 1) — full unroll makes
// the allocator rematerialize afrag global loads inside the loop (R5: VGPR
// dropped 128->112, MfmaUtil 24->9.8%, 2.5x slower).
// NOTE: do NOT raise min-waves/EU — (256,4) capped regs at 128/wave and
// spilled afrag to scratch (R4: FETCH 612 MB, 4x slower).
__global__ __launch_bounds__(256, 2)
void k_main(const __hip_bfloat16* __restrict__ znh, float* __restrict__ rowsum,
            const float* __restrict__ pos_part, unsigned* __restrict__ done_ctr,
            float* __restrict__ out) {
    __shared__ __align__(16) ushort zj[TJ * ZJ_STRIDE];   // 33792 B
    const ushort* zn = reinterpret_cast<const ushort*>(znh);
    int tid  = threadIdx.x;
    int wave = tid >> 6;
    int lane = tid & 63;
    int q    = lane >> 4;   // quad
    int li   = lane & 15;
    int i_base = blockIdx.x * 256 + wave * 64;
    int j0     = blockIdx.y * JCHUNK;

    // A fragment (16x16x32 bf16): A[m][k], m = lane&15, k = quad*8 + j
    bf16x8 afrag[4][8];
#pragma unroll
    for (int it = 0; it < 4; ++it) {
        const ushort* ap = zn + (((size_t)(i_base + it * 16 + li)) << 8) + q * 8;
#pragma unroll
        for (int kt = 0; kt < 8; ++kt)
            afrag[it][kt] = *reinterpret_cast<const bf16x8*>(ap + kt * 32);
    }

    float part[4][4];   // [i_tile][reg-row]
#pragma unroll
    for (int it = 0; it < 4; ++it)
#pragma unroll
        for (int r = 0; r < 4; ++r) part[it][r] = 0.0f;

    // Prefetch B tile 0 into registers (this thread's share: 8 x 16B).
    uint4 pre[8];
#pragma unroll
    for (int s = 0; s < 8; ++s) {
        int e  = (s * 256 + tid) * 8;
        int rr = e >> 8;
        int cc = e & 255;
        pre[s] = *reinterpret_cast<const uint4*>(zn + (((size_t)(j0 + rr)) << 8) + cc);
    }

#pragma unroll 1
    for (int jt = 0; jt < NJT; ++jt) {
        __syncthreads();   // previous iteration's reads done before overwrite
#pragma unroll
        for (int s = 0; s < 8; ++s) {
            int e  = (s * 256 + tid) * 8;
            int rr = e >> 8;
            int cc = e & 255;
            *reinterpret_cast<uint4*>(&zj[rr * ZJ_STRIDE + cc]) = pre[s];
        }
        __syncthreads();

        // Issue next tile's global loads now; they retire under the MFMA work.
        {
            int nb = j0 + (jt + 1 < NJT ? jt + 1 : jt) * TJ;
#pragma unroll
            for (int s = 0; s < 8; ++s) {
                int e  = (s * 256 + tid) * 8;
                int rr = e >> 8;
                int cc = e & 255;
                pre[s] = *reinterpret_cast<const uint4*>(zn + (((size_t)(nb + rr)) << 8) + cc);
            }
        }

#pragma unroll
        for (int jtile = 0; jtile < 4; ++jtile) {
            f32x4 acc[4] = {{0,0,0,0},{0,0,0,0},{0,0,0,0},{0,0,0,0}};
#pragma unroll
            for (int kt = 0; kt < 8; ++kt) {
                // B frag: B[k][n], n = li -> zj row (jtile*16 + li), k = kt*32 + q*8
                bf16x8 b = *reinterpret_cast<const bf16x8*>(
                    &zj[(jtile * 16 + li) * ZJ_STRIDE + kt * 32 + q * 8]);
#pragma unroll
                for (int it = 0; it < 4; ++it)
                    acc[it] = __builtin_amdgcn_mfma_f32_16x16x32_bf16(
                        afrag[it][kt], b, acc[it], 0, 0, 0);
            }
            // C/D layout (m89-verified): col = lane&15, row = quad*4 + reg
            // exp(2s-2) = exp2(2log2e*s - 2log2e): one v_fma + one v_exp
#pragma unroll
            for (int it = 0; it < 4; ++it)
#pragma unroll
                for (int r = 0; r < 4; ++r)
                    part[it][r] += exp2f(__builtin_fmaf(acc[it][r], C_LOG2E_2, -C_LOG2E_2));
        }
    }

    // Reduce across the 16 lanes holding different j-cols of the same rows.
#pragma unroll
    for (int it = 0; it < 4; ++it)
#pragma unroll
        for (int r = 0; r < 4; ++r) {
            float v = part[it][r];
            v += __shfl_xor(v, 1);
            v += __shfl_xor(v, 2);
            v += __shfl_xor(v, 4);
            v += __shfl_xor(v, 8);
            if (li == 0) atomicAdd(&rowsum[i_base + it * 16 + q * 4 + r], v);
        }

    // Last-block-done: final reduction fused in (saves a ~20us launch gap).
    __threadfence();
    __shared__ unsigned lastv;
    if (tid == 0) lastv = atomicAdd(done_ctr, 1u);
    __syncthreads();
    if (lastv == NBLOCKS - 1) {
        float acc = 0.0f;
        for (int i = tid; i < M_TOT; i += 256) {
            float v = atomicAdd(&rowsum[i], 0.0f);   // coherent read
            acc += 2.0f + __logf(v - 1.0f);          // lse_i (diag's exp(0)=1 removed)
        }
        float pacc = 0.0f;
        for (int i = tid; i < N_HALF; i += 256)
            pacc += pos_part[i];
        acc  = wave_reduce_sum(acc);
        pacc = wave_reduce_sum(pacc);
        __shared__ float wsum[4], psum[4];
        if ((tid & 63) == 0) { wsum[tid >> 6] = acc; psum[tid >> 6] = pacc; }
        __syncthreads();
        if (tid == 0) {
            float tot = wsum[0] + wsum[1] + wsum[2] + wsum[3];
            float pt  = psum[0] + psum[1] + psum[2] + psum[3];
            out[0] = (tot - pt) / (float)M_TOT;
        }
    }
}

extern "C" void kernel_launch(void* const* d_in, const int* in_sizes, int n_in,
                              void* d_out, int out_size, void* d_ws, size_t ws_size,
                              hipStream_t stream) {
    const float* zis = (const float*)d_in[0];
    const float* zjs = (const float*)d_in[1];
    char* ws = (char*)d_ws;
    __hip_bfloat16* zn = (__hip_bfloat16*)ws;                         // 4 MB
    float* rowsum   = (float*)(ws + (size_t)M_TOT * D * 2);           // 32 KB
    float* pos_part = rowsum + M_TOT;                                 // 16 KB
    unsigned* done_ctr = (unsigned*)(pos_part + N_HALF);              // 4 B

    k_prep<<<N_HALF / 4, 256, 0, stream>>>(zis, zjs, zn, rowsum, pos_part, done_ctr);
    dim3 grid(M_TOT / 256, M_TOT / JCHUNK);
    k_main<<<grid, 256, 0, stream>>>(zn, rowsum, pos_part, done_ctr, (float*)d_out);
}